// Round 12
// baseline (27.214 us; speedup 1.0000x reference)
//
#include <hip/hip_runtime.h>

#define BATCH 8192

typedef __attribute__((ext_vector_type(8))) short bf16x8;
typedef __attribute__((ext_vector_type(4))) float f32x4;

__device__ __forceinline__ unsigned short f2bf(float f) {
    unsigned int u = __float_as_uint(f);
    u += 0x7fffu + ((u >> 16) & 1u);      // RTNE
    return (unsigned short)(u >> 16);
}
__device__ __forceinline__ float rdl(float v, int lane) {
    return __int_as_float(__builtin_amdgcn_readlane(__float_as_int(v), lane));
}

// ---------------------------------------------------------------------------
// Kernel 1 (R9-verified, unchanged): U columns, 256 blocks x 64 threads.
// Ub[512][256] bf16: rows 0-255 Re, rows 256-511 Im; column c = basis state.
// ---------------------------------------------------------------------------
__global__ __launch_bounds__(64) void ukern(const float* __restrict__ w,
                                            unsigned short* __restrict__ Ub)
{
    const int l = threadIdx.x;
    const int c = blockIdx.x;

    float v0, v1, v2, v3;
    {
        const int t  = l & 31;
        const int li = t >> 3;
        const int wi = t & 7;
        float th = w[(li * 8 + wi) * 2 + 0];
        float ph = w[(li * 8 + wi) * 2 + 1];
        float cth = __cosf(0.5f * th), sth = __sinf(0.5f * th);
        if (wi < 6) {
            float cph = __cosf(0.5f * ph), sph = __sinf(0.5f * ph);
            v0 = cth * cph;  v1 = cth * sph;  v2 = sth * cph;  v3 = sth * sph;
        } else {
            v0 = cth;  v1 = sth;  v2 = __cosf(ph);  v3 = __sinf(ph);
        }
    }

    float re[4], im[4];
    const bool ls = (l == (c >> 2));
    #pragma unroll
    for (int k = 0; k < 4; ++k) {
        re[k] = (ls && ((c & 3) == k)) ? 1.0f : 0.0f;
        im[k] = 0.0f;
    }
    const int  src = (l ^ (l >> 1)) & 63;
    const bool c5  = (l & 1);

    #pragma unroll
    for (int layer = 0; layer < 4; ++layer) {
        const int lb = layer * 8;
        float tr[4], ti[4];
        #pragma unroll
        for (int k = 0; k < 4; ++k) {
            tr[k] = __shfl(re[k], src, 64);
            ti[k] = __shfl(im[k], src, 64);
        }
        re[0] = c5 ? tr[2] : tr[0];  im[0] = c5 ? ti[2] : ti[0];
        re[1] = c5 ? tr[3] : tr[1];  im[1] = c5 ? ti[3] : ti[1];
        re[2] = c5 ? tr[1] : tr[3];  im[2] = c5 ? ti[1] : ti[3];
        re[3] = c5 ? tr[0] : tr[2];  im[3] = c5 ? ti[0] : ti[2];
        re[1] = __shfl_xor(re[1], 32, 64); im[1] = __shfl_xor(im[1], 32, 64);
        re[3] = __shfl_xor(re[3], 32, 64); im[3] = __shfl_xor(im[3], 32, 64);

        #pragma unroll
        for (int i = 0; i < 6; ++i) {
            float Ar = rdl(v0, lb + i);
            float SZ = rdl(v3, lb + i);
            float sgn = (l & (32 >> i)) ? 1.0f : -1.0f;
            float Ai = sgn * rdl(v1, lb + i);
            float Br = sgn * rdl(v2, lb + i);
            const int m = 32 >> i;
            #pragma unroll
            for (int k = 0; k < 4; ++k) {
                float br = __shfl_xor(re[k], m, 64);
                float bi = __shfl_xor(im[k], m, 64);
                float ar = re[k], ai = im[k];
                re[k] = Ar*ar - Ai*ai + Br*br + SZ*bi;
                im[k] = Ar*ai + Ai*ar + Br*bi - SZ*br;
            }
        }
        #pragma unroll
        for (int i = 0; i < 2; ++i) {
            float cy = rdl(v0, lb + 6 + i);
            float sy = rdl(v1, lb + 6 + i);
            float cf = rdl(v2, lb + 6 + i);
            float sf = rdl(v3, lb + 6 + i);
            const int mk = 2 >> i;
            #pragma unroll
            for (int k = 0; k < 4; ++k) {
                if (!(k & mk)) continue;
                float r = re[k], q = im[k];
                re[k] = r * cf - q * sf;
                im[k] = q * cf + r * sf;
            }
            #pragma unroll
            for (int k = 0; k < 4; ++k) {
                if (k & mk) continue;
                int k1 = k | mk;
                float ar = re[k], ai = im[k], br = re[k1], bi = im[k1];
                re[k]  = cy * ar - sy * br;
                im[k]  = cy * ai - sy * bi;
                re[k1] = sy * ar + cy * br;
                im[k1] = sy * ai + cy * bi;
            }
        }
    }
    #pragma unroll
    for (int k = 0; k < 4; ++k) {
        int i = l * 4 + k;
        Ub[i * 256 + c]         = f2bf(re[k]);
        Ub[(256 + i) * 256 + c] = f2bf(im[k]);
    }
}

// ---------------------------------------------------------------------------
// Kernel 2: M-split. 512 blocks x 512 threads; block (sb = bid&255,
// half = bid>>8) covers samples [32*sb, 32*sb+32) x amps [128*half, +128).
// 4096 waves total -> 4 waves/SIMD (2 co-resident blocks/CU), same total
// A-traffic as R9. Wave wid owns 16 amps (2 MFMA M-tiles: Re, Im).
// Amp-index bits: half=bit7(wire0), wid=bits6..4(wires1-3),
// kgrp=bits3..2(wires4-5), r=bits1..0(wires6-7).
// Outputs combined across the 2 half-blocks via atomicAdd (out pre-zeroed).
// ---------------------------------------------------------------------------
__global__ __launch_bounds__(512) void qmain(const float* __restrict__ x,
                                             const float* __restrict__ w,
                                             const unsigned short* __restrict__ Ub,
                                             float* __restrict__ out)
{
    __shared__ float trg[32][17];              // [sample][wire]=cos, [8+wire]=sin
    __shared__ unsigned short psi[32 * 264];   // 32 samples x 256 amps, stride 264
    __shared__ float Ps[8][289];               // per-wave epilogue partials
    const int tid  = threadIdx.x;
    const int wid  = tid >> 6;
    const int lane = tid & 63;
    const int sb   = blockIdx.x & 255;
    const int half = blockIdx.x >> 8;
    const int s0   = sb * 32;

    // ---- phase 0: trig, one (sample,wire) pair per thread (R9-verified) ----
    if (tid < 256) {
        const int s  = tid >> 3;
        const int wi = tid & 7;
        float a = 0.5f * (x[(s0 + s) * 8 + wi] + w[2 * wi]);
        trg[s][wi]     = __cosf(a);
        trg[s][8 + wi] = __sinf(a);
    }
    __syncthreads();

    // ---- phase 1: psi chunk (16 amps) per thread (R9-verified) ----
    {
        const int s  = tid >> 4;
        const int j1 = tid & 15;
        float c0 = trg[s][0], c1 = trg[s][1], c2 = trg[s][2], c3 = trg[s][3];
        float s0w = trg[s][8], s1w = trg[s][9], s2w = trg[s][10], s3w = trg[s][11];
        float A1 = ((j1 & 8) ? s0w : c0) * ((j1 & 4) ? s1w : c1)
                 * ((j1 & 2) ? s2w : c2) * ((j1 & 1) ? s3w : c3);
        float c4 = trg[s][4], c5 = trg[s][5], c6 = trg[s][6], c7 = trg[s][7];
        float s4 = trg[s][12], s5 = trg[s][13], s6 = trg[s][14], s7 = trg[s][15];
        float q45[4] = {A1 * c4 * c5, A1 * c4 * s5, A1 * s4 * c5, A1 * s4 * s5};
        float p67[4] = {c6 * c7, c6 * s7, s6 * c7, s6 * s7};
        unsigned int wbuf[8];
        #pragma unroll
        for (int p = 0; p < 8; ++p) {
            int ja = 2 * p, jb = 2 * p + 1;
            float va = q45[ja >> 2] * p67[ja & 3];
            float vb = q45[jb >> 2] * p67[jb & 3];
            wbuf[p] = (unsigned int)f2bf(va) | ((unsigned int)f2bf(vb) << 16);
        }
        uint4* dst = (uint4*)((char*)psi + s * 528 + j1 * 32);
        dst[0] = make_uint4(wbuf[0], wbuf[1], wbuf[2], wbuf[3]);
        dst[1] = make_uint4(wbuf[4], wbuf[5], wbuf[6], wbuf[7]);
    }
    __syncthreads();

    // ---- phase 2: GEMM; wave wid owns amps [128*half + 16*wid, +16) ----
    const int mrow = lane & 15;
    const int kgrp = lane >> 4;
    const int aw0  = half * 128 + wid * 16;

    f32x4 acc[2][2];   // mt: 0 = Re tile, 1 = Im tile; nt 0..1
    #pragma unroll
    for (int a = 0; a < 2; ++a)
        #pragma unroll
        for (int b = 0; b < 2; ++b)
            acc[a][b] = (f32x4){0.f, 0.f, 0.f, 0.f};

    #pragma unroll
    for (int ks = 0; ks < 8; ++ks) {
        const int k0 = ks * 32 + kgrp * 8;
        bf16x8 bfr0 = *(const bf16x8*)(psi + mrow * 264 + k0);
        bf16x8 bfr1 = *(const bf16x8*)(psi + (16 + mrow) * 264 + k0);
        bf16x8 afr0 = *(const bf16x8*)(Ub + (aw0 + mrow) * 256 + k0);
        bf16x8 afr1 = *(const bf16x8*)(Ub + (256 + aw0 + mrow) * 256 + k0);
        acc[0][0] = __builtin_amdgcn_mfma_f32_16x16x32_bf16(afr0, bfr0, acc[0][0], 0, 0, 0);
        acc[0][1] = __builtin_amdgcn_mfma_f32_16x16x32_bf16(afr0, bfr1, acc[0][1], 0, 0, 0);
        acc[1][0] = __builtin_amdgcn_mfma_f32_16x16x32_bf16(afr1, bfr0, acc[1][0], 0, 0, 0);
        acc[1][1] = __builtin_amdgcn_mfma_f32_16x16x32_bf16(afr1, bfr1, acc[1][1], 0, 0, 0);
    }

    // ---- epilogue: amp = 128*half + 16*wid + 4*kgrp + r ----
    #pragma unroll
    for (int nt = 0; nt < 2; ++nt) {
        float p0 = acc[0][nt][0]*acc[0][nt][0] + acc[1][nt][0]*acc[1][nt][0];
        float p1 = acc[0][nt][1]*acc[0][nt][1] + acc[1][nt][1]*acc[1][nt][1];
        float p2 = acc[0][nt][2]*acc[0][nt][2] + acc[1][nt][2]*acc[1][nt][2];
        float p3 = acc[0][nt][3]*acc[0][nt][3] + acc[1][nt][3]*acc[1][nt][3];
        float t0 = p0 + p1, t1 = p2 + p3;
        float ps = t0 + t1;
        float m6 = t0 - t1;                        // wire6: sign by r&2
        float m7 = (p0 - p1) + (p2 - p3);          // wire7: sign by r&1
        float m0 = half       ? -ps : ps;          // wire0: bit7
        float m1 = (wid & 4)  ? -ps : ps;          // wire1: bit6
        float m2 = (wid & 2)  ? -ps : ps;          // wire2: bit5
        float m3 = (wid & 1)  ? -ps : ps;          // wire3: bit4
        float m4 = (kgrp & 2) ? -ps : ps;          // wire4: bit3
        float m5 = (kgrp & 1) ? -ps : ps;          // wire5: bit2
        m0 += __shfl_xor(m0, 16, 64);  m0 += __shfl_xor(m0, 32, 64);
        m1 += __shfl_xor(m1, 16, 64);  m1 += __shfl_xor(m1, 32, 64);
        m2 += __shfl_xor(m2, 16, 64);  m2 += __shfl_xor(m2, 32, 64);
        m3 += __shfl_xor(m3, 16, 64);  m3 += __shfl_xor(m3, 32, 64);
        m4 += __shfl_xor(m4, 16, 64);  m4 += __shfl_xor(m4, 32, 64);
        m5 += __shfl_xor(m5, 16, 64);  m5 += __shfl_xor(m5, 32, 64);
        m6 += __shfl_xor(m6, 16, 64);  m6 += __shfl_xor(m6, 32, 64);
        m7 += __shfl_xor(m7, 16, 64);  m7 += __shfl_xor(m7, 32, 64);
        if (kgrp == 0) {
            const int snt = nt * 16 + mrow;
            float* pp = &Ps[wid][snt * 9];
            pp[0]=m0; pp[1]=m1; pp[2]=m2; pp[3]=m3; pp[4]=m4; pp[5]=m5; pp[6]=m6; pp[7]=m7;
        }
    }
    __syncthreads();
    if (tid < 64) {
        const int s  = tid & 31;
        const int hq = tid >> 5;
        float r0 = 0.f, r1 = 0.f, r2 = 0.f, r3 = 0.f;
        #pragma unroll
        for (int uu = 0; uu < 8; ++uu) {
            const float* pp = &Ps[uu][s * 9 + hq * 4];
            r0 += pp[0]; r1 += pp[1]; r2 += pp[2]; r3 += pp[3];
        }
        float* o = out + (s0 + s) * 8 + hq * 4;
        atomicAdd(o + 0, r0);
        atomicAdd(o + 1, r1);
        atomicAdd(o + 2, r2);
        atomicAdd(o + 3, r3);
    }
}

extern "C" void kernel_launch(void* const* d_in, const int* in_sizes, int n_in,
                              void* d_out, int out_size, void* d_ws, size_t ws_size,
                              hipStream_t stream)
{
    const float* x = (const float*)d_in[0];
    const float* w = (const float*)d_in[1];
    unsigned short* Ub = (unsigned short*)d_ws;   // 256 KiB
    hipMemsetAsync(d_out, 0, (size_t)out_size * sizeof(float), stream);
    ukern<<<256, 64, 0, stream>>>(w, Ub);
    qmain<<<512, 512, 0, stream>>>(x, w, Ub, (float*)d_out);
}

// Round 13
// 19.319 us; speedup vs baseline: 1.4087x; 1.4087x over previous
//
#include <hip/hip_runtime.h>

#define BATCH 8192

typedef __attribute__((ext_vector_type(8))) short bf16x8;
typedef __attribute__((ext_vector_type(4))) float f32x4;

__device__ __forceinline__ unsigned short f2bf(float f) {
    unsigned int u = __float_as_uint(f);
    u += 0x7fffu + ((u >> 16) & 1u);      // RTNE
    return (unsigned short)(u >> 16);
}
__device__ __forceinline__ float rdl(float v, int lane) {
    return __int_as_float(__builtin_amdgcn_readlane(__float_as_int(v), lane));
}

// ---------------------------------------------------------------------------
// Kernel 1: U columns, 256 blocks x 64 threads (R9-verified circuit).
// NEW storage layout (fragment-contiguous for qmain's A-loads):
//   elem(i,c) at  (i>>4)*4096 + (c>>5)*512 + ((c>>3)&3)*128 + (i&15)*8 + (c&7)
//   Re tiles t=i>>4 in [0,16); Im at +65536 elems. Total 256 KiB.
// A wave's fragment (t, ks) = 64 lanes x 16 B = ONE contiguous 1 KiB block.
// ---------------------------------------------------------------------------
__global__ __launch_bounds__(64) void ukern(const float* __restrict__ w,
                                            unsigned short* __restrict__ Ub)
{
    const int l = threadIdx.x;
    const int c = blockIdx.x;

    float v0, v1, v2, v3;
    {
        const int t  = l & 31;
        const int li = t >> 3;
        const int wi = t & 7;
        float th = w[(li * 8 + wi) * 2 + 0];
        float ph = w[(li * 8 + wi) * 2 + 1];
        float cth = __cosf(0.5f * th), sth = __sinf(0.5f * th);
        if (wi < 6) {
            float cph = __cosf(0.5f * ph), sph = __sinf(0.5f * ph);
            v0 = cth * cph;  v1 = cth * sph;  v2 = sth * cph;  v3 = sth * sph;
        } else {
            v0 = cth;  v1 = sth;  v2 = __cosf(ph);  v3 = __sinf(ph);
        }
    }

    float re[4], im[4];
    const bool ls = (l == (c >> 2));
    #pragma unroll
    for (int k = 0; k < 4; ++k) {
        re[k] = (ls && ((c & 3) == k)) ? 1.0f : 0.0f;
        im[k] = 0.0f;
    }
    const int  src = (l ^ (l >> 1)) & 63;
    const bool c5  = (l & 1);

    #pragma unroll
    for (int layer = 0; layer < 4; ++layer) {
        const int lb = layer * 8;
        float tr[4], ti[4];
        #pragma unroll
        for (int k = 0; k < 4; ++k) {
            tr[k] = __shfl(re[k], src, 64);
            ti[k] = __shfl(im[k], src, 64);
        }
        re[0] = c5 ? tr[2] : tr[0];  im[0] = c5 ? ti[2] : ti[0];
        re[1] = c5 ? tr[3] : tr[1];  im[1] = c5 ? ti[3] : ti[1];
        re[2] = c5 ? tr[1] : tr[3];  im[2] = c5 ? ti[1] : ti[3];
        re[3] = c5 ? tr[0] : tr[2];  im[3] = c5 ? ti[0] : ti[2];
        re[1] = __shfl_xor(re[1], 32, 64); im[1] = __shfl_xor(im[1], 32, 64);
        re[3] = __shfl_xor(re[3], 32, 64); im[3] = __shfl_xor(im[3], 32, 64);

        #pragma unroll
        for (int i = 0; i < 6; ++i) {
            float Ar = rdl(v0, lb + i);
            float SZ = rdl(v3, lb + i);
            float sgn = (l & (32 >> i)) ? 1.0f : -1.0f;
            float Ai = sgn * rdl(v1, lb + i);
            float Br = sgn * rdl(v2, lb + i);
            const int m = 32 >> i;
            #pragma unroll
            for (int k = 0; k < 4; ++k) {
                float br = __shfl_xor(re[k], m, 64);
                float bi = __shfl_xor(im[k], m, 64);
                float ar = re[k], ai = im[k];
                re[k] = Ar*ar - Ai*ai + Br*br + SZ*bi;
                im[k] = Ar*ai + Ai*ar + Br*bi - SZ*br;
            }
        }
        #pragma unroll
        for (int i = 0; i < 2; ++i) {
            float cy = rdl(v0, lb + 6 + i);
            float sy = rdl(v1, lb + 6 + i);
            float cf = rdl(v2, lb + 6 + i);
            float sf = rdl(v3, lb + 6 + i);
            const int mk = 2 >> i;
            #pragma unroll
            for (int k = 0; k < 4; ++k) {
                if (!(k & mk)) continue;
                float r = re[k], q = im[k];
                re[k] = r * cf - q * sf;
                im[k] = q * cf + r * sf;
            }
            #pragma unroll
            for (int k = 0; k < 4; ++k) {
                if (k & mk) continue;
                int k1 = k | mk;
                float ar = re[k], ai = im[k], br = re[k1], bi = im[k1];
                re[k]  = cy * ar - sy * br;
                im[k]  = cy * ai - sy * bi;
                re[k1] = sy * ar + cy * br;
                im[k1] = sy * ai + cy * bi;
            }
        }
    }
    const int cterm = (c >> 5) * 512 + ((c >> 3) & 3) * 128 + (c & 7);
    #pragma unroll
    for (int k = 0; k < 4; ++k) {
        int i = l * 4 + k;
        int base = (i >> 4) * 4096 + (i & 15) * 8 + cterm;
        Ub[base]         = f2bf(re[k]);
        Ub[base + 65536] = f2bf(im[k]);
    }
}

// ---------------------------------------------------------------------------
// Kernel 2 (R9 structure): 256 blocks x 512 threads (8 waves, 2/SIMD).
// Phase 0: trig once per (sample,wire) -> trg LDS.
// Phase 1: psi (32 samples x 256 amps bf16) in LDS.
// Phase 2: GEMM C[512][32] = U*psi; A-fragments are contiguous 1 KiB loads
//          (new Ub layout) with a 1-deep double buffer; fused epilogue.
// Amp-index bit (7-w) = wire w: wid = bits 7..5, mtl = bit 4, kgrp = bits 3..2,
// r = bits 1..0.  [R8/R9-verified mapping]
// ---------------------------------------------------------------------------
__global__ __launch_bounds__(512) void qmain(const float* __restrict__ x,
                                             const float* __restrict__ w,
                                             const unsigned short* __restrict__ Ub,
                                             float* __restrict__ out)
{
    __shared__ float trg[32][17];              // [sample][wire]=cos, [8+wire]=sin
    __shared__ unsigned short psi[32 * 264];   // 32 samples x 256 amps, stride 264
    __shared__ float Ps[8][289];               // per-wave epilogue partials
    const int tid  = threadIdx.x;
    const int wid  = tid >> 6;
    const int lane = tid & 63;
    const int bid  = blockIdx.x;
    const int s0   = bid * 32;

    // ---- phase 0: trig, one (sample,wire) pair per thread ----
    if (tid < 256) {
        const int s  = tid >> 3;
        const int wi = tid & 7;
        float a = 0.5f * (x[(s0 + s) * 8 + wi] + w[2 * wi]);
        trg[s][wi]     = __cosf(a);
        trg[s][8 + wi] = __sinf(a);
    }
    __syncthreads();

    // ---- phase 1: psi chunk (16 amps) per thread ----
    {
        const int s  = tid >> 4;
        const int j1 = tid & 15;
        float c0 = trg[s][0], c1 = trg[s][1], c2 = trg[s][2], c3 = trg[s][3];
        float s0w = trg[s][8], s1w = trg[s][9], s2w = trg[s][10], s3w = trg[s][11];
        float A1 = ((j1 & 8) ? s0w : c0) * ((j1 & 4) ? s1w : c1)
                 * ((j1 & 2) ? s2w : c2) * ((j1 & 1) ? s3w : c3);
        float c4 = trg[s][4], c5 = trg[s][5], c6 = trg[s][6], c7 = trg[s][7];
        float s4 = trg[s][12], s5 = trg[s][13], s6 = trg[s][14], s7 = trg[s][15];
        float q45[4] = {A1 * c4 * c5, A1 * c4 * s5, A1 * s4 * c5, A1 * s4 * s5};
        float p67[4] = {c6 * c7, c6 * s7, s6 * c7, s6 * s7};
        unsigned int wbuf[8];
        #pragma unroll
        for (int p = 0; p < 8; ++p) {
            int ja = 2 * p, jb = 2 * p + 1;
            float va = q45[ja >> 2] * p67[ja & 3];
            float vb = q45[jb >> 2] * p67[jb & 3];
            wbuf[p] = (unsigned int)f2bf(va) | ((unsigned int)f2bf(vb) << 16);
        }
        uint4* dst = (uint4*)((char*)psi + s * 528 + j1 * 32);
        dst[0] = make_uint4(wbuf[0], wbuf[1], wbuf[2], wbuf[3]);
        dst[1] = make_uint4(wbuf[4], wbuf[5], wbuf[6], wbuf[7]);
    }
    __syncthreads();

    // ---- phase 2: GEMM; A contiguous-fragment loads + 1-deep double buffer ----
    const int mrow = lane & 15;
    const int kgrp = lane >> 4;
    const int t0   = wid * 2;
    const unsigned short* A = Ub + kgrp * 128 + mrow * 8;

    f32x4 acc[4][2];
    #pragma unroll
    for (int a = 0; a < 4; ++a)
        #pragma unroll
        for (int b = 0; b < 2; ++b)
            acc[a][b] = (f32x4){0.f, 0.f, 0.f, 0.f};

    bf16x8 a0 = *(const bf16x8*)(A + (t0     ) * 4096);
    bf16x8 a1 = *(const bf16x8*)(A + (t0 +  1) * 4096);
    bf16x8 a2 = *(const bf16x8*)(A + (t0 + 16) * 4096);
    bf16x8 a3 = *(const bf16x8*)(A + (t0 + 17) * 4096);

    #pragma unroll
    for (int ks = 0; ks < 8; ++ks) {
        bf16x8 n0 = a0, n1 = a1, n2 = a2, n3 = a3;
        if (ks < 7) {
            const int nk = (ks + 1) * 512;
            n0 = *(const bf16x8*)(A + (t0     ) * 4096 + nk);
            n1 = *(const bf16x8*)(A + (t0 +  1) * 4096 + nk);
            n2 = *(const bf16x8*)(A + (t0 + 16) * 4096 + nk);
            n3 = *(const bf16x8*)(A + (t0 + 17) * 4096 + nk);
        }
        const int k0 = ks * 32 + kgrp * 8;
        bf16x8 bfr0 = *(const bf16x8*)(psi + mrow * 264 + k0);
        bf16x8 bfr1 = *(const bf16x8*)(psi + (16 + mrow) * 264 + k0);
        acc[0][0] = __builtin_amdgcn_mfma_f32_16x16x32_bf16(a0, bfr0, acc[0][0], 0, 0, 0);
        acc[0][1] = __builtin_amdgcn_mfma_f32_16x16x32_bf16(a0, bfr1, acc[0][1], 0, 0, 0);
        acc[1][0] = __builtin_amdgcn_mfma_f32_16x16x32_bf16(a1, bfr0, acc[1][0], 0, 0, 0);
        acc[1][1] = __builtin_amdgcn_mfma_f32_16x16x32_bf16(a1, bfr1, acc[1][1], 0, 0, 0);
        acc[2][0] = __builtin_amdgcn_mfma_f32_16x16x32_bf16(a2, bfr0, acc[2][0], 0, 0, 0);
        acc[2][1] = __builtin_amdgcn_mfma_f32_16x16x32_bf16(a2, bfr1, acc[2][1], 0, 0, 0);
        acc[3][0] = __builtin_amdgcn_mfma_f32_16x16x32_bf16(a3, bfr0, acc[3][0], 0, 0, 0);
        acc[3][1] = __builtin_amdgcn_mfma_f32_16x16x32_bf16(a3, bfr1, acc[3][1], 0, 0, 0);
        a0 = n0; a1 = n1; a2 = n2; a3 = n3;
    }

    // ---- epilogue: amp = 32*wid + mtl*16 + kgrp*4 + r; reduce kgrp in-wave ----
    #pragma unroll
    for (int nt = 0; nt < 2; ++nt) {
        float am[2], r2m[2], r1m[2];
        #pragma unroll
        for (int mtl = 0; mtl < 2; ++mtl) {
            float p0 = acc[mtl][nt][0]*acc[mtl][nt][0] + acc[mtl+2][nt][0]*acc[mtl+2][nt][0];
            float p1 = acc[mtl][nt][1]*acc[mtl][nt][1] + acc[mtl+2][nt][1]*acc[mtl+2][nt][1];
            float p2 = acc[mtl][nt][2]*acc[mtl][nt][2] + acc[mtl+2][nt][2]*acc[mtl+2][nt][2];
            float p3 = acc[mtl][nt][3]*acc[mtl][nt][3] + acc[mtl+2][nt][3]*acc[mtl+2][nt][3];
            float t0s = p0 + p1, t1s = p2 + p3;
            am[mtl]  = t0s + t1s;
            r2m[mtl] = t0s - t1s;                  // wire6: sign by r&2
            r1m[mtl] = (p0 - p1) + (p2 - p3);      // wire7: sign by r&1
        }
        float ps = am[0] + am[1];
        float m3 = am[0] - am[1];                  // wire3: bit4 = mtl
        float m6 = r2m[0] + r2m[1];
        float m7 = r1m[0] + r1m[1];
        float m0 = (wid & 4)  ? -ps : ps;          // wire0: bit7
        float m1 = (wid & 2)  ? -ps : ps;          // wire1: bit6
        float m2 = (wid & 1)  ? -ps : ps;          // wire2: bit5
        float m4 = (kgrp & 2) ? -ps : ps;          // wire4: bit3
        float m5 = (kgrp & 1) ? -ps : ps;          // wire5: bit2
        m0 += __shfl_xor(m0, 16, 64);  m0 += __shfl_xor(m0, 32, 64);
        m1 += __shfl_xor(m1, 16, 64);  m1 += __shfl_xor(m1, 32, 64);
        m2 += __shfl_xor(m2, 16, 64);  m2 += __shfl_xor(m2, 32, 64);
        m3 += __shfl_xor(m3, 16, 64);  m3 += __shfl_xor(m3, 32, 64);
        m4 += __shfl_xor(m4, 16, 64);  m4 += __shfl_xor(m4, 32, 64);
        m5 += __shfl_xor(m5, 16, 64);  m5 += __shfl_xor(m5, 32, 64);
        m6 += __shfl_xor(m6, 16, 64);  m6 += __shfl_xor(m6, 32, 64);
        m7 += __shfl_xor(m7, 16, 64);  m7 += __shfl_xor(m7, 32, 64);
        if (kgrp == 0) {
            const int snt = nt * 16 + mrow;
            float* pp = &Ps[wid][snt * 9];
            pp[0]=m0; pp[1]=m1; pp[2]=m2; pp[3]=m3; pp[4]=m4; pp[5]=m5; pp[6]=m6; pp[7]=m7;
        }
    }
    __syncthreads();
    if (tid < 64) {
        const int s    = tid & 31;
        const int half = tid >> 5;
        float r0 = 0.f, r1 = 0.f, r2 = 0.f, r3 = 0.f;
        #pragma unroll
        for (int uu = 0; uu < 8; ++uu) {
            const float* pp = &Ps[uu][s * 9 + half * 4];
            r0 += pp[0]; r1 += pp[1]; r2 += pp[2]; r3 += pp[3];
        }
        float4* o = (float4*)(out + (s0 + s) * 8 + half * 4);
        *o = make_float4(r0, r1, r2, r3);
    }
}

extern "C" void kernel_launch(void* const* d_in, const int* in_sizes, int n_in,
                              void* d_out, int out_size, void* d_ws, size_t ws_size,
                              hipStream_t stream)
{
    const float* x = (const float*)d_in[0];
    const float* w = (const float*)d_in[1];
    unsigned short* Ub = (unsigned short*)d_ws;   // 256 KiB
    ukern<<<256, 64, 0, stream>>>(w, Ub);
    qmain<<<256, 512, 0, stream>>>(x, w, Ub, (float*)d_out);
}